// Round 1
// 288.745 us; speedup vs baseline: 1.0809x; 1.0809x over previous
//
#include <hip/hip_runtime.h>
#include <hip/hip_bf16.h>

// FourierKANLayer: N=4096, D_IN=512, D_OUT=512, G=32
// y = [cos/sin(k*LN(x)) features] @ W + bias  == GEMM M=4096,N=512,K=32768 (bf16 MFMA)
// R8: counted-vmcnt pipeline (T3/T4/T5). B tri-buffer ring staged via
//     global_load_lds depth-2 prefetch; A single buffer with pre-barrier
//     register fragment reads. Raw s_barrier + asm waitcnt fences;
//     vmcnt never drained to 0 in the main loop. 64KB LDS, 2 blocks/CU.
// ws layout: [0,16MB)  csT float2[512][4096] = (cos xn, sin xn) transposed seeds
//            [16MB]    mu_rs float2[4096] (32 KB)
//            [17MB]    bf16 weights [2][512][16384] K-major (33.5 MB)
//            [51MB]    bf16 split-K partials [4][4096][512] (16.8 MB)

#define N_ROWS 4096
#define D_IN   512
#define D_OUT  512
#define KT     16384   // per-trig K = D_IN*G
#define BM 128
#define BN 128
#define SPLITK 4

typedef short short8 __attribute__((ext_vector_type(8)));
typedef float float4v __attribute__((ext_vector_type(4)));

__device__ inline unsigned int pack2bf(float a, float b) {
    __hip_bfloat162 h = __float22bfloat162_rn(make_float2(a, b));
    union { __hip_bfloat162 h; unsigned int u; } cv;
    cv.h = h;
    return cv.u;
}

__device__ inline unsigned short bf16_1(float a) {
    union { float f; unsigned int u; } cv;
    cv.f = a;
    unsigned int r = (cv.u + 0x7fff + ((cv.u >> 16) & 1)) >> 16;  // RN-even
    return (unsigned short)r;
}

// ---- kernel 1: per-row LayerNorm stats (mu, rsqrt(var+eps)) ----
__global__ __launch_bounds__(256) void ln_stats(const float* __restrict__ x,
        float2* __restrict__ mu_rs) {
    const int t = threadIdx.x;
    const int row = blockIdx.x * 4 + (t >> 6);
    const int lane = t & 63;
    const float4* xr = (const float4*)(x + (size_t)row * D_IN);
    float4 a = xr[lane];
    float4 c = xr[lane + 64];
    float s = a.x + a.y + a.z + a.w + c.x + c.y + c.z + c.w;
    float q = a.x * a.x + a.y * a.y + a.z * a.z + a.w * a.w
            + c.x * c.x + c.y * c.y + c.z * c.z + c.w * c.w;
    #pragma unroll
    for (int off = 32; off > 0; off >>= 1) {
        s += __shfl_down(s, off, 64);
        q += __shfl_down(q, off, 64);
    }
    if (lane == 0) {
        float mu = s * (1.f / D_IN);
        float var = q * (1.f / D_IN) - mu * mu;
        mu_rs[row] = make_float2(mu, rsqrtf(var + 1e-5f));
    }
}

// ---- kernel 2: normalize + sincos seeds, transposed coalesced write ----
// R8: tile transposed to [row][dim] with 65-pad: write phase is now
// conflict-free (was 16-way: stride 132 dwords == 4 mod 32); read ~4-way.
__global__ __launch_bounds__(256) void feat_seed(const float* __restrict__ x,
        const float* __restrict__ w, const float* __restrict__ b,
        const float2* __restrict__ mu_rs, float2* __restrict__ csT) {
    __shared__ float2 tile[64][65];
    const int t = threadIdx.x;
    const int r0 = blockIdx.x * 64, i0 = blockIdx.y * 64;
    const int rr = t >> 6;      // 0..3
    const int cc = t & 63;
    const float wv = w[i0 + cc], bv = b[i0 + cc];
    #pragma unroll
    for (int p = 0; p < 16; ++p) {
        const int row = r0 + p * 4 + rr;
        float v = x[(size_t)row * D_IN + i0 + cc];
        float2 mr = mu_rs[row];
        float xn = (v - mr.x) * mr.y * wv + bv;
        float sn, cn;
        __sincosf(xn, &sn, &cn);
        tile[p * 4 + rr][cc] = make_float2(cn, sn);   // contiguous in cc: no conflict
    }
    __syncthreads();
    #pragma unroll
    for (int p = 0; p < 16; ++p) {
        const int dim = p * 4 + rr;
        csT[(size_t)(i0 + dim) * N_ROWS + r0 + cc] = tile[cc][dim];
    }
}

// ---- kernel 3: cast fouriercoeffs fp32 -> bf16 (layout preserved: [t][o][i*32+g]) ----
__global__ __launch_bounds__(256) void cvt_kernel(const float* __restrict__ fc,
        unsigned short* __restrict__ Wb) {
    size_t e = ((size_t)blockIdx.x * 256 + threadIdx.x) * 8;
    const float4* in = (const float4*)(fc + e);
    float4 a = in[0];
    float4 c = in[1];
    uint4 o;
    o.x = pack2bf(a.x, a.y);
    o.y = pack2bf(a.z, a.w);
    o.z = pack2bf(c.x, c.y);
    o.w = pack2bf(c.z, c.w);
    *(uint4*)(Wb + e) = o;
}

// ---- feature staging: Chebyshev chain -> swizzled A LDS tile ----
// A layout: [row][64 shorts], 16B chunk kc stored at chunk index kc^(row&7).
__device__ inline void stage_feats(unsigned short* Abuf, float2 cs, int ttype,
                                   int frow, int ihalf) {
    const float c1 = cs.x, s1 = cs.y;
    const float c2 = c1 + c1;
    float prev = ttype ? 0.f : 1.f;
    float cur  = ttype ? s1 : c1;
    const int rbase = frow * 64;
    const int sw = frow & 7;
    unsigned int us[4];
    #pragma unroll
    for (int d = 0; d < 16; ++d) {
        float f0 = cur;
        float f1 = __builtin_fmaf(c2, cur, -prev);
        float f2 = __builtin_fmaf(c2, f1, -cur);
        prev = f1;
        cur = f2;
        us[d & 3] = pack2bf(f0, f1);
        if ((d & 3) == 3) {
            const int kc = ihalf * 4 + (d >> 2);
            *(uint4*)&Abuf[rbase + ((kc ^ sw) << 3)] =
                make_uint4(us[0], us[1], us[2], us[3]);
        }
    }
}

__device__ inline void gl_lds16(const unsigned short* gsrc, unsigned short* ldst) {
    __builtin_amdgcn_global_load_lds(
        (const __attribute__((address_space(1))) unsigned int*)gsrc,
        (__attribute__((address_space(3))) unsigned int*)ldst, 16, 0, 0);
}

__device__ inline void read_af(const unsigned short* As, short8 (&af)[2][4],
                               int wm, int lm, int lq, int swA) {
    #pragma unroll
    for (int h = 0; h < 2; ++h)
        #pragma unroll
        for (int tm = 0; tm < 4; ++tm)
            af[h][tm] = *(const short8*)
                &As[(wm + tm * 16 + lm) * 64 + (((h * 4 + lq) ^ swA) << 3)];
}

__device__ inline void read_bf(const unsigned short* Bp, short8 (&bf)[2][4],
                               int bBase) {
    #pragma unroll
    for (int h = 0; h < 2; ++h)
        #pragma unroll
        for (int tn = 0; tn < 4; ++tn)
            bf[h][tn] = *(const short8*)&Bp[bBase + tn * 1024 + h * 256];
}

__device__ inline void mfma_block(short8 (&af)[2][4], short8 (&bf)[2][4],
                                  float4v (&acc)[4][4]) {
    __builtin_amdgcn_s_setprio(1);
    #pragma unroll
    for (int h = 0; h < 2; ++h)
        #pragma unroll
        for (int tm = 0; tm < 4; ++tm)
            #pragma unroll
            for (int tn = 0; tn < 4; ++tn)
                acc[tm][tn] = __builtin_amdgcn_mfma_f32_16x16x32_bf16(
                    af[h][tm], bf[h][tn], acc[tm][tn], 0, 0, 0);
    __builtin_amdgcn_s_setprio(0);
}

// ---- kernel 4: fused feature-gen + bf16 MFMA GEMM, split-K=4, trig-merged ----
// grid (32 row-tiles, 4 col-tiles, 4 k-chunks). 128 K-iters: 0..63 cos, 64..127 sin.
// Pipeline: B(n) lives in Bs[n%3], issued at iter n-2 (counted vmcnt, never 0).
// A single-buffered: fragments register-read pre-barrier, restaged post-barrier.
__global__ __launch_bounds__(256, 2) void fkan_gemm(const float2* __restrict__ csT,
        const unsigned short* __restrict__ Wb, unsigned short* __restrict__ pb) {
    __shared__ unsigned short As[BM * 64];      // 16 KB, swizzled, single buffer
    __shared__ unsigned short Bs[3][BN * 64];   // 3 x 16 KB ring (gl_lds dest)
    const int t = threadIdx.x;
    const int row0 = blockIdx.x * BM;
    const int col0 = blockIdx.y * BN;
    const int kz = blockIdx.z;
    const int k0 = kz * 4096;            // within-trig k offset
    const int i0 = kz * 128;             // starting input dim for this chunk
    const int frow = t & 127;            // A-staging row
    const int ihalf = t >> 7;            // which of the 2 dims per iter
    const int l = t & 63, wv = t >> 6;
    const int wm = (wv & 1) * 64, wn = (wv >> 1) * 64;
    const int lm = l & 15, lq = l >> 4;
    // gl_lds B staging: wave wv covers cols [col0+wv*32, +32), 4 instr x (8 cols x 128B)
    const int c8 = l & 7, s8 = l >> 3;   // lane -> (col-within-8, 16B-segment)
    const unsigned short* Bg0 = Wb + (size_t)(col0 + wv * 32 + c8) * KT + k0 + s8 * 8;
    const int swA = lm & 7;
    // B-frag read base (shorts): gi*512 + s*64 + ci*8
    const int bBase = ((wn >> 3) + (lm >> 3)) * 512 + lq * 64 + (lm & 7) * 8;

    const float2* csBase = csT + (size_t)(i0 + ihalf) * N_ROWS + row0 + frow;

    float4v acc[4][4];
    #pragma unroll
    for (int i = 0; i < 4; ++i)
        #pragma unroll
        for (int j = 0; j < 4; ++j)
            acc[i][j] = (float4v){0.f, 0.f, 0.f, 0.f};

    // ---- prologue: B(0)->Bs[0], B(1)->Bs[1] (grouped so vmcnt(4) covers B(0)),
    //      stage A(0), preload seeds(1).
    #pragma unroll
    for (int j = 0; j < 4; ++j)
        gl_lds16(Bg0 + (size_t)(j * 8) * KT, &Bs[0][(wv * 4 + j) * 512]);
    #pragma unroll
    for (int j = 0; j < 4; ++j)
        gl_lds16(Bg0 + 64 + (size_t)(j * 8) * KT, &Bs[1][(wv * 4 + j) * 512]);
    {
        float2 c0 = csBase[0];
        float2 tmp = csBase[2 * N_ROWS];
        stage_feats(As, c0, 0, frow, ihalf);
        // keep seeds(1) in csA below
        asm volatile("s_waitcnt vmcnt(4) lgkmcnt(0)" ::: "memory");
        __builtin_amdgcn_s_barrier();
        // ---- main loop: iters 0..125, branch-free body
        float2 csA = tmp;                 // seeds for A(it+1)
        int rd = 0, wr = 2;
        for (int it = 0; it < 126; ++it) {
            const unsigned short* Bp = &Bs[rd][0];
            // S1: A fragments -> regs (A gets restaged after the barrier)
            short8 af[2][4];
            read_af(As, af, wm, lm, lq, swA);
            // S2: issue B(it+2) -> Bs[wr]  (depth-2 prefetch)
            {
                const int in = it + 2;
                const unsigned short* gb =
                    Bg0 + (size_t)(in >> 6) * D_OUT * KT + (in & 63) * 64;
                #pragma unroll
                for (int j = 0; j < 4; ++j)
                    gl_lds16(gb + (size_t)(j * 8) * KT, &Bs[wr][(wv * 4 + j) * 512]);
            }
            asm volatile("s_waitcnt lgkmcnt(0)" ::: "memory");   // my A reads done
            __builtin_amdgcn_s_barrier();
            // S3: seeds(it+2); S4: restage A(it+1); S5: B frags + MFMA
            float2 csN = csBase[(size_t)(((it + 2) & 63) * 2) * N_ROWS];
            stage_feats(As, csA, (it + 1) >> 6, frow, ihalf);
            csA = csN;
            short8 bf[2][4];
            read_bf(Bp, bf, bBase);
            mfma_block(af, bf, acc);
            // B(it+1) drained; B(it+2)x4 + seeds(it+2) stay in flight
            asm volatile("s_waitcnt vmcnt(5) lgkmcnt(0)" ::: "memory");
            __builtin_amdgcn_s_barrier();
            rd = (rd == 2) ? 0 : rd + 1;
            wr = (wr == 2) ? 0 : wr + 1;
        }
        // ---- iter 126: no prefetch; publish A(127), drain B(127)
        {
            const unsigned short* Bp = &Bs[0][0];   // 126 % 3 == 0
            short8 af[2][4];
            read_af(As, af, wm, lm, lq, swA);
            asm volatile("s_waitcnt lgkmcnt(0)" ::: "memory");
            __builtin_amdgcn_s_barrier();
            stage_feats(As, csA, 1, frow, ihalf);   // A(127), sin plane
            short8 bf[2][4];
            read_bf(Bp, bf, bBase);
            mfma_block(af, bf, acc);
            asm volatile("s_waitcnt vmcnt(0) lgkmcnt(0)" ::: "memory");
            __builtin_amdgcn_s_barrier();
        }
        // ---- iter 127: pure compute (compiler-managed waits)
        {
            const unsigned short* Bp = &Bs[1][0];   // 127 % 3 == 1
            short8 af[2][4];
            read_af(As, af, wm, lm, lq, swA);
            short8 bf[2][4];
            read_bf(Bp, bf, bBase);
            mfma_block(af, bf, acc);
        }
    }
    // epilogue: C/D layout col=lane&15, row=quad*4+reg (m89-verified)
    unsigned short* pc = pb + (size_t)kz * N_ROWS * D_OUT;
    #pragma unroll
    for (int tm = 0; tm < 4; ++tm)
        #pragma unroll
        for (int tn = 0; tn < 4; ++tn)
            #pragma unroll
            for (int r = 0; r < 4; ++r) {
                const int row = row0 + wm + tm * 16 + lq * 4 + r;
                const int col = col0 + wn + tn * 16 + lm;
                pc[(size_t)row * D_OUT + col] = bf16_1(acc[tm][tn][r]);
            }
}

// ---- kernel 5: out = bias + sum of 4 bf16 partials (coalesced) ----
__global__ __launch_bounds__(256) void reduce_kernel(const unsigned short* __restrict__ pb,
        const float* __restrict__ bias, float* __restrict__ out) {
    const size_t e = ((size_t)blockIdx.x * 256 + threadIdx.x) * 4;
    const int col = (int)(e & (D_OUT - 1));
    float4 s = *(const float4*)(bias + col);
    #pragma unroll
    for (int c = 0; c < SPLITK; ++c) {
        ushort4 u = *(const ushort4*)(pb + (size_t)c * N_ROWS * D_OUT + e);
        union { unsigned int u; float f; } f0, f1, f2, f3;
        f0.u = (unsigned int)u.x << 16;
        f1.u = (unsigned int)u.y << 16;
        f2.u = (unsigned int)u.z << 16;
        f3.u = (unsigned int)u.w << 16;
        s.x += f0.f; s.y += f1.f; s.z += f2.f; s.w += f3.f;
    }
    *(float4*)(out + e) = s;
}

extern "C" void kernel_launch(void* const* d_in, const int* in_sizes, int n_in,
                              void* d_out, int out_size, void* d_ws, size_t ws_size,
                              hipStream_t stream) {
    const float* x    = (const float*)d_in[0];
    const float* ln_w = (const float*)d_in[1];
    const float* ln_b = (const float*)d_in[2];
    const float* fc   = (const float*)d_in[3];
    const float* bias = (const float*)d_in[4];
    float* out = (float*)d_out;

    float2* csT = (float2*)d_ws;                                        // 16 MB
    float2* mu_rs = (float2*)((char*)d_ws + (16u << 20));               // 32 KB
    unsigned short* Wb = (unsigned short*)((char*)d_ws + (17u << 20));  // 33.5 MB
    unsigned short* pbp = (unsigned short*)((char*)d_ws + (51u << 20)); // 16.8 MB

    ln_stats<<<N_ROWS / 4, 256, 0, stream>>>(x, mu_rs);
    feat_seed<<<dim3(N_ROWS / 64, D_IN / 64), 256, 0, stream>>>(x, ln_w, ln_b, mu_rs, csT);
    cvt_kernel<<<8192, 256, 0, stream>>>(fc, Wb);                       // 16.78M elems
    fkan_gemm<<<dim3(N_ROWS / BM, D_OUT / BN, SPLITK), 256, 0, stream>>>(csT, Wb, pbp);
    reduce_kernel<<<2048, 256, 0, stream>>>(pbp, bias, out);            // 2.10M outs
}

// Round 2
// 283.877 us; speedup vs baseline: 1.0994x; 1.0171x over previous
//
#include <hip/hip_runtime.h>
#include <hip/hip_bf16.h>

// FourierKANLayer: N=4096, D_IN=512, D_OUT=512, G=32
// y = [cos/sin(k*LN(x)) features] @ W + bias  == GEMM M=4096,N=512,K=32768 (bf16 MFMA)
// R9: ONE barrier per K-iter. A double-buffered (2x16KB) + B tri-buffer ring
//     (3x16KB) staged via global_load_lds depth-2 prefetch, counted vmcnt(5)
//     (never 0 in main loop). 80KB LDS/block -> 2 blocks/CU = 160KB exact fit.
//     Whole iter is one scheduling region: ds_reads + Chebyshev A-restage +
//     MFMA co-scheduled; single fence {vmcnt(5) lgkmcnt(0); s_barrier}.
// ws layout: [0,16MB)  csT float2[512][4096] = (cos xn, sin xn) transposed seeds
//            [16MB]    mu_rs float2[4096] (32 KB)
//            [17MB]    bf16 weights [2][512][16384] K-major (33.5 MB)
//            [51MB]    bf16 split-K partials [4][4096][512] (16.8 MB)

#define N_ROWS 4096
#define D_IN   512
#define D_OUT  512
#define KT     16384   // per-trig K = D_IN*G
#define BM 128
#define BN 128
#define SPLITK 4

typedef short short8 __attribute__((ext_vector_type(8)));
typedef float float4v __attribute__((ext_vector_type(4)));

__device__ inline unsigned int pack2bf(float a, float b) {
    __hip_bfloat162 h = __float22bfloat162_rn(make_float2(a, b));
    union { __hip_bfloat162 h; unsigned int u; } cv;
    cv.h = h;
    return cv.u;
}

__device__ inline unsigned short bf16_1(float a) {
    union { float f; unsigned int u; } cv;
    cv.f = a;
    unsigned int r = (cv.u + 0x7fff + ((cv.u >> 16) & 1)) >> 16;  // RN-even
    return (unsigned short)r;
}

// ---- kernel 1: per-row LayerNorm stats (mu, rsqrt(var+eps)) ----
__global__ __launch_bounds__(256) void ln_stats(const float* __restrict__ x,
        float2* __restrict__ mu_rs) {
    const int t = threadIdx.x;
    const int row = blockIdx.x * 4 + (t >> 6);
    const int lane = t & 63;
    const float4* xr = (const float4*)(x + (size_t)row * D_IN);
    float4 a = xr[lane];
    float4 c = xr[lane + 64];
    float s = a.x + a.y + a.z + a.w + c.x + c.y + c.z + c.w;
    float q = a.x * a.x + a.y * a.y + a.z * a.z + a.w * a.w
            + c.x * c.x + c.y * c.y + c.z * c.z + c.w * c.w;
    #pragma unroll
    for (int off = 32; off > 0; off >>= 1) {
        s += __shfl_down(s, off, 64);
        q += __shfl_down(q, off, 64);
    }
    if (lane == 0) {
        float mu = s * (1.f / D_IN);
        float var = q * (1.f / D_IN) - mu * mu;
        mu_rs[row] = make_float2(mu, rsqrtf(var + 1e-5f));
    }
}

// ---- kernel 2: normalize + sincos seeds, transposed coalesced write ----
// tile [row][dim] with 65-pad: write phase conflict-free, read ~4-way.
__global__ __launch_bounds__(256) void feat_seed(const float* __restrict__ x,
        const float* __restrict__ w, const float* __restrict__ b,
        const float2* __restrict__ mu_rs, float2* __restrict__ csT) {
    __shared__ float2 tile[64][65];
    const int t = threadIdx.x;
    const int r0 = blockIdx.x * 64, i0 = blockIdx.y * 64;
    const int rr = t >> 6;      // 0..3
    const int cc = t & 63;
    const float wv = w[i0 + cc], bv = b[i0 + cc];
    #pragma unroll
    for (int p = 0; p < 16; ++p) {
        const int row = r0 + p * 4 + rr;
        float v = x[(size_t)row * D_IN + i0 + cc];
        float2 mr = mu_rs[row];
        float xn = (v - mr.x) * mr.y * wv + bv;
        float sn, cn;
        __sincosf(xn, &sn, &cn);
        tile[p * 4 + rr][cc] = make_float2(cn, sn);   // contiguous in cc: no conflict
    }
    __syncthreads();
    #pragma unroll
    for (int p = 0; p < 16; ++p) {
        const int dim = p * 4 + rr;
        csT[(size_t)(i0 + dim) * N_ROWS + r0 + cc] = tile[cc][dim];
    }
}

// ---- kernel 3: cast fouriercoeffs fp32 -> bf16 (layout preserved: [t][o][i*32+g]) ----
__global__ __launch_bounds__(256) void cvt_kernel(const float* __restrict__ fc,
        unsigned short* __restrict__ Wb) {
    size_t e = ((size_t)blockIdx.x * 256 + threadIdx.x) * 8;
    const float4* in = (const float4*)(fc + e);
    float4 a = in[0];
    float4 c = in[1];
    uint4 o;
    o.x = pack2bf(a.x, a.y);
    o.y = pack2bf(a.z, a.w);
    o.z = pack2bf(c.x, c.y);
    o.w = pack2bf(c.z, c.w);
    *(uint4*)(Wb + e) = o;
}

// ---- feature staging: Chebyshev chain -> swizzled A LDS tile ----
// A layout: [row][64 shorts], 16B chunk kc stored at chunk index kc^(row&7).
__device__ inline void stage_feats(unsigned short* Abuf, float2 cs, int ttype,
                                   int frow, int ihalf) {
    const float c1 = cs.x, s1 = cs.y;
    const float c2 = c1 + c1;
    float prev = ttype ? 0.f : 1.f;
    float cur  = ttype ? s1 : c1;
    const int rbase = frow * 64;
    const int sw = frow & 7;
    unsigned int us[4];
    #pragma unroll
    for (int d = 0; d < 16; ++d) {
        float f0 = cur;
        float f1 = __builtin_fmaf(c2, cur, -prev);
        float f2 = __builtin_fmaf(c2, f1, -cur);
        prev = f1;
        cur = f2;
        us[d & 3] = pack2bf(f0, f1);
        if ((d & 3) == 3) {
            const int kc = ihalf * 4 + (d >> 2);
            *(uint4*)&Abuf[rbase + ((kc ^ sw) << 3)] =
                make_uint4(us[0], us[1], us[2], us[3]);
        }
    }
}

__device__ inline void gl_lds16(const unsigned short* gsrc, unsigned short* ldst) {
    __builtin_amdgcn_global_load_lds(
        (const __attribute__((address_space(1))) unsigned int*)gsrc,
        (__attribute__((address_space(3))) unsigned int*)ldst, 16, 0, 0);
}

__device__ inline void read_af(const unsigned short* As, short8 (&af)[2][4],
                               int wm, int lm, int lq, int swA) {
    #pragma unroll
    for (int h = 0; h < 2; ++h)
        #pragma unroll
        for (int tm = 0; tm < 4; ++tm)
            af[h][tm] = *(const short8*)
                &As[(wm + tm * 16 + lm) * 64 + (((h * 4 + lq) ^ swA) << 3)];
}

__device__ inline void read_bf(const unsigned short* Bp, short8 (&bf)[2][4],
                               int bBase) {
    #pragma unroll
    for (int h = 0; h < 2; ++h)
        #pragma unroll
        for (int tn = 0; tn < 4; ++tn)
            bf[h][tn] = *(const short8*)&Bp[bBase + tn * 1024 + h * 256];
}

__device__ inline void mfma_block(short8 (&af)[2][4], short8 (&bf)[2][4],
                                  float4v (&acc)[4][4]) {
    __builtin_amdgcn_s_setprio(1);
    #pragma unroll
    for (int h = 0; h < 2; ++h)
        #pragma unroll
        for (int tm = 0; tm < 4; ++tm)
            #pragma unroll
            for (int tn = 0; tn < 4; ++tn)
                acc[tm][tn] = __builtin_amdgcn_mfma_f32_16x16x32_bf16(
                    af[h][tm], bf[h][tn], acc[tm][tn], 0, 0, 0);
    __builtin_amdgcn_s_setprio(0);
}

// ---- kernel 4: fused feature-gen + bf16 MFMA GEMM, split-K=4, trig-merged ----
// grid (32 row-tiles, 4 col-tiles, 4 k-chunks). 128 K-iters: 0..63 cos, 64..127 sin.
// B(n) lives in Bs[n%3], issued at iter n-2 (counted vmcnt, never 0 mid-loop).
// A(n) lives in As[n&1], staged at iter n-1. ONE barrier per iter.
__global__ __launch_bounds__(256, 2) void fkan_gemm(const float2* __restrict__ csT,
        const unsigned short* __restrict__ Wb, unsigned short* __restrict__ pb) {
    __shared__ unsigned short As[2][BM * 64];   // 2 x 16 KB, swizzled
    __shared__ unsigned short Bs[3][BN * 64];   // 3 x 16 KB ring (gl_lds dest)
    const int t = threadIdx.x;
    const int row0 = blockIdx.x * BM;
    const int col0 = blockIdx.y * BN;
    const int kz = blockIdx.z;
    const int k0 = kz * 4096;            // within-trig k offset
    const int i0 = kz * 128;             // starting input dim for this chunk
    const int frow = t & 127;            // A-staging row
    const int ihalf = t >> 7;            // which of the 2 dims per iter
    const int l = t & 63, wv = t >> 6;
    const int wm = (wv & 1) * 64, wn = (wv >> 1) * 64;
    const int lm = l & 15, lq = l >> 4;
    // gl_lds B staging: wave wv covers cols [col0+wv*32, +32), 4 instr x (8 cols x 128B)
    const int c8 = l & 7, s8 = l >> 3;   // lane -> (col-within-8, 16B-segment)
    const unsigned short* Bg0 = Wb + (size_t)(col0 + wv * 32 + c8) * KT + k0 + s8 * 8;
    const int swA = lm & 7;
    // B-frag read base (shorts): gi*512 + s*64 + ci*8
    const int bBase = ((wn >> 3) + (lm >> 3)) * 512 + lq * 64 + (lm & 7) * 8;

    const float2* csBase = csT + (size_t)(i0 + ihalf) * N_ROWS + row0 + frow;

    float4v acc[4][4];
    #pragma unroll
    for (int i = 0; i < 4; ++i)
        #pragma unroll
        for (int j = 0; j < 4; ++j)
            acc[i][j] = (float4v){0.f, 0.f, 0.f, 0.f};

    // ---- prologue: B(0)->Bs[0], B(1)->Bs[1]; stage A(0)->As[0]; seeds(1).
    #pragma unroll
    for (int j = 0; j < 4; ++j)
        gl_lds16(Bg0 + (size_t)(j * 8) * KT, &Bs[0][(wv * 4 + j) * 512]);
    #pragma unroll
    for (int j = 0; j < 4; ++j)
        gl_lds16(Bg0 + 64 + (size_t)(j * 8) * KT, &Bs[1][(wv * 4 + j) * 512]);
    float2 c0 = csBase[0];
    float2 csA = csBase[2 * N_ROWS];     // seeds for A(1)
    stage_feats(&As[0][0], c0, 0, frow, ihalf);
    asm volatile("s_waitcnt vmcnt(4) lgkmcnt(0)" ::: "memory");  // B(0) landed
    __builtin_amdgcn_s_barrier();

    // ---- main loop: iters 0..125, one barrier per iter
    int rd = 0, wr = 2;
    for (int it = 0; it < 126; ++it) {
        const int p = it & 1;
        const unsigned short* Bp = &Bs[0][0] + rd * (BN * 64);
        // issue B(it+2) -> Bs[wr]  (depth-2 prefetch, longest latency first)
        {
            const int in = it + 2;
            const unsigned short* gb =
                Bg0 + (size_t)(in >> 6) * D_OUT * KT + (in & 63) * 64;
            unsigned short* ldst = &Bs[0][0] + wr * (BN * 64) + (wv * 4) * 512;
            #pragma unroll
            for (int j = 0; j < 4; ++j)
                gl_lds16(gb + (size_t)(j * 8) * KT, ldst + j * 512);
        }
        // seeds(it+2)
        float2 csN = csBase[(size_t)(((it + 2) & 63) * 2) * N_ROWS];
        // fragments from published buffers
        short8 af[2][4];
        read_af(&As[p][0], af, wm, lm, lq, swA);
        short8 bf[2][4];
        read_bf(Bp, bf, bBase);
        // restage A(it+1) into the other buffer (overlaps MFMA)
        stage_feats(&As[p ^ 1][0], csA, (it + 1) >> 6, frow, ihalf);
        csA = csN;
        mfma_block(af, bf, acc);
        // B(it+1) drained; B(it+2)x4 + seeds(it+2) stay in flight. Publish A(it+1).
        asm volatile("s_waitcnt vmcnt(5) lgkmcnt(0)" ::: "memory");
        __builtin_amdgcn_s_barrier();
        rd = (rd == 2) ? 0 : rd + 1;
        wr = (wr == 2) ? 0 : wr + 1;
    }
    // ---- iter 126: no prefetch; stage A(127); drain everything
    {
        const unsigned short* Bp = &Bs[0][0];   // 126 % 3 == 0
        short8 af[2][4];
        read_af(&As[0][0], af, wm, lm, lq, swA);
        short8 bf[2][4];
        read_bf(Bp, bf, bBase);
        stage_feats(&As[1][0], csA, 1, frow, ihalf);   // A(127), sin plane
        mfma_block(af, bf, acc);
        asm volatile("s_waitcnt vmcnt(0) lgkmcnt(0)" ::: "memory");
        __builtin_amdgcn_s_barrier();
    }
    // ---- iter 127: pure compute (compiler-managed waits)
    {
        const unsigned short* Bp = &Bs[1][0];   // 127 % 3 == 1
        short8 af[2][4];
        read_af(&As[1][0], af, wm, lm, lq, swA);
        short8 bf[2][4];
        read_bf(Bp, bf, bBase);
        mfma_block(af, bf, acc);
    }
    // epilogue: C/D layout col=lane&15, row=quad*4+reg (m89-verified)
    unsigned short* pc = pb + (size_t)kz * N_ROWS * D_OUT;
    #pragma unroll
    for (int tm = 0; tm < 4; ++tm)
        #pragma unroll
        for (int tn = 0; tn < 4; ++tn)
            #pragma unroll
            for (int r = 0; r < 4; ++r) {
                const int row = row0 + wm + tm * 16 + lq * 4 + r;
                const int col = col0 + wn + tn * 16 + lm;
                pc[(size_t)row * D_OUT + col] = bf16_1(acc[tm][tn][r]);
            }
}

// ---- kernel 5: out = bias + sum of 4 bf16 partials (coalesced) ----
__global__ __launch_bounds__(256) void reduce_kernel(const unsigned short* __restrict__ pb,
        const float* __restrict__ bias, float* __restrict__ out) {
    const size_t e = ((size_t)blockIdx.x * 256 + threadIdx.x) * 4;
    const int col = (int)(e & (D_OUT - 1));
    float4 s = *(const float4*)(bias + col);
    #pragma unroll
    for (int c = 0; c < SPLITK; ++c) {
        ushort4 u = *(const ushort4*)(pb + (size_t)c * N_ROWS * D_OUT + e);
        union { unsigned int u; float f; } f0, f1, f2, f3;
        f0.u = (unsigned int)u.x << 16;
        f1.u = (unsigned int)u.y << 16;
        f2.u = (unsigned int)u.z << 16;
        f3.u = (unsigned int)u.w << 16;
        s.x += f0.f; s.y += f1.f; s.z += f2.f; s.w += f3.f;
    }
    *(float4*)(out + e) = s;
}

extern "C" void kernel_launch(void* const* d_in, const int* in_sizes, int n_in,
                              void* d_out, int out_size, void* d_ws, size_t ws_size,
                              hipStream_t stream) {
    const float* x    = (const float*)d_in[0];
    const float* ln_w = (const float*)d_in[1];
    const float* ln_b = (const float*)d_in[2];
    const float* fc   = (const float*)d_in[3];
    const float* bias = (const float*)d_in[4];
    float* out = (float*)d_out;

    float2* csT = (float2*)d_ws;                                        // 16 MB
    float2* mu_rs = (float2*)((char*)d_ws + (16u << 20));               // 32 KB
    unsigned short* Wb = (unsigned short*)((char*)d_ws + (17u << 20));  // 33.5 MB
    unsigned short* pbp = (unsigned short*)((char*)d_ws + (51u << 20)); // 16.8 MB

    ln_stats<<<N_ROWS / 4, 256, 0, stream>>>(x, mu_rs);
    feat_seed<<<dim3(N_ROWS / 64, D_IN / 64), 256, 0, stream>>>(x, ln_w, ln_b, mu_rs, csT);
    cvt_kernel<<<8192, 256, 0, stream>>>(fc, Wb);                       // 16.78M elems
    fkan_gemm<<<dim3(N_ROWS / BM, D_OUT / BN, SPLITK), 256, 0, stream>>>(csT, Wb, pbp);
    reduce_kernel<<<2048, 256, 0, stream>>>(pbp, bias, out);            // 2.10M outs
}